// Round 1
// 514.143 us; speedup vs baseline: 1.0786x; 1.0786x over previous
//
#include <hip/hip_runtime.h>
#include <hip/hip_bf16.h>

using bf16 = __hip_bfloat16;
typedef short  short8  __attribute__((ext_vector_type(8)));
typedef float  float4_ __attribute__((ext_vector_type(4)));
typedef int    int4_   __attribute__((ext_vector_type(4)));

typedef __attribute__((address_space(1))) const void* gas_ptr;
typedef __attribute__((address_space(3))) void*       las_ptr;

#define MFMA_BF16(a, b, c) __builtin_amdgcn_mfma_f32_16x16x32_bf16((a), (b), (c), 0, 0, 0)

__device__ __forceinline__ float bf2f(bf16 v) { return __bfloat162float(v); }
__device__ __forceinline__ bf16  f2bf(float v) { return __float2bfloat16(v); }

// ---------------------------------------------------------------------------
// fp32 -> bf16 conversion of X + 4 weights into workspace (verified r2 form).
// ---------------------------------------------------------------------------
__global__ __launch_bounds__(256)
void cvt_all(const float* __restrict__ X,  const float* __restrict__ Wq,
             const float* __restrict__ Wk, const float* __restrict__ Wv,
             const float* __restrict__ Wo,
             bf16* __restrict__ Xb,  bf16* __restrict__ Wqb,
             bf16* __restrict__ Wkb, bf16* __restrict__ Wvb,
             bf16* __restrict__ Wob)
{
    const size_t i = ((size_t)blockIdx.x * 256 + threadIdx.x) * 8;
    const float* src; bf16* dst; size_t off;
    if (i < 8388608)       { src = X;  dst = Xb;  off = i; }
    else if (i < 12582912) { src = Wq; dst = Wqb; off = i - 8388608; }
    else if (i < 16777216) { src = Wk; dst = Wkb; off = i - 12582912; }
    else if (i < 20971520) { src = Wv; dst = Wvb; off = i - 16777216; }
    else                   { src = Wo; dst = Wob; off = i - 20971520; }
    const float4_ a = *(const float4_*)(src + off);
    const float4_ b = *(const float4_*)(src + off + 4);
    union { short8 s; bf16 h[8]; } u;
#pragma unroll
    for (int j = 0; j < 4; ++j) { u.h[j] = f2bf(a[j]); u.h[j + 4] = f2bf(b[j]); }
    *(short8*)(dst + off) = u.s;
}

// ---------------------------------------------------------------------------
// MFMA GEMM (function-verified r2-4): C[4096][2048] = A * W^T, bf16, fp32 acc.
// m97 structure: 128x128 tile, 4 waves 2x2, global_load_lds w=16, BK=32.
// mode 0: scatter bf16 to Out[b][h][s][d] (qkv). mode 1: row-major fp32 OutF.
// ---------------------------------------------------------------------------
__global__ __launch_bounds__(256)
void gemm128(const bf16* __restrict__ A,
             const bf16* __restrict__ W0, const bf16* __restrict__ W1, const bf16* __restrict__ W2,
             bf16* __restrict__ O0, bf16* __restrict__ O1, bf16* __restrict__ O2,
             float* __restrict__ OF, int mode)
{
    constexpr int K = 2048;
    const int z = blockIdx.z;
    const bf16* W  = (z == 0) ? W0 : (z == 1) ? W1 : W2;
    bf16*      Out = (z == 0) ? O0 : (z == 1) ? O1 : O2;

    const int bm = blockIdx.y * 128;
    const int bn = blockIdx.x * 128;

    const int tid  = threadIdx.x;
    const int wave = tid >> 6;
    const int ln   = tid & 63;
    const int r15  = ln & 15;
    const int quad = ln >> 4;
    const int wr   = wave >> 1, wc = wave & 1;

    __shared__ bf16 As[128 * 32];
    __shared__ bf16 Bs[128 * 32];

    float4_ acc[4][4];
    const float4_ fzero = {0.f, 0.f, 0.f, 0.f};
#pragma unroll
    for (int i = 0; i < 4; ++i)
#pragma unroll
        for (int j = 0; j < 4; ++j) acc[i][j] = fzero;

    const int srow = ln >> 2;
    const int scg  = (ln & 3) * 8;

    for (int kt = 0; kt < K / 32; ++kt) {
        const int k0 = kt * 32;
#pragma unroll
        for (int c = 0; c < 2; ++c) {
            const int rb = (wave * 2 + c) * 16;
            const bf16* ga = A + (size_t)(bm + rb + srow) * K + k0 + scg;
            const bf16* gb = W + (size_t)(bn + rb + srow) * K + k0 + scg;
            __builtin_amdgcn_global_load_lds((gas_ptr)ga, (las_ptr)(&As[rb * 32]), 16, 0, 0);
            __builtin_amdgcn_global_load_lds((gas_ptr)gb, (las_ptr)(&Bs[rb * 32]), 16, 0, 0);
        }
        __syncthreads();

        short8 af[4], bfr[4];
#pragma unroll
        for (int i = 0; i < 4; ++i)
            af[i] = *(const short8*)&As[(wr * 64 + i * 16 + r15) * 32 + quad * 8];
#pragma unroll
        for (int j = 0; j < 4; ++j)
            bfr[j] = *(const short8*)&Bs[(wc * 64 + j * 16 + r15) * 32 + quad * 8];
#pragma unroll
        for (int i = 0; i < 4; ++i)
#pragma unroll
            for (int j = 0; j < 4; ++j)
                acc[i][j] = MFMA_BF16(af[i], bfr[j], acc[i][j]);
        __syncthreads();
    }

#pragma unroll
    for (int i = 0; i < 4; ++i) {
#pragma unroll
        for (int j = 0; j < 4; ++j) {
#pragma unroll
            for (int r = 0; r < 4; ++r) {
                const int row = bm + wr * 64 + i * 16 + quad * 4 + r;
                const int col = bn + wc * 64 + j * 16 + r15;
                const float v = acc[i][j][r];
                if (mode == 0) {
                    const int b = row >> 11, s = row & 2047;
                    const int h = col >> 7,  d = col & 127;
                    Out[(((size_t)b * 16 + h) * 2048 + s) * 128 + d] = f2bf(v);
                } else {
                    OF[(size_t)row * 2048 + col] = v;   // fp32 final output
                }
            }
        }
    }
}

// ---------------------------------------------------------------------------
// RoPE on Q and K ([B][NH][S][HD] bf16); folds 1/sqrt(128) into Q.
// ---------------------------------------------------------------------------
__global__ __launch_bounds__(256)
void rope_scale(bf16* __restrict__ Q, bf16* __restrict__ Kb)
{
    const int idx = blockIdx.x * 256 + threadIdx.x;
    const int d  = idx & 63;
    const int s  = (idx >> 6) & 2047;
    const int bh = idx >> 17;
    const size_t base = ((size_t)bh * 2048 + s) * 128;

    const float inv_freq = expf(-(float)d * (9.210340371976184f / 64.f));
    const float ang = (float)s * inv_freq;
    const float c = cosf(ang), sn = sinf(ang);
    const float sc = 0.08838834764831845f;

    const float q1 = bf2f(Q[base + d]), q2 = bf2f(Q[base + d + 64]);
    Q[base + d]      = f2bf((q1 * c - q2 * sn) * sc);
    Q[base + d + 64] = f2bf((q2 * c + q1 * sn) * sc);

    const float k1 = bf2f(Kb[base + d]), k2 = bf2f(Kb[base + d + 64]);
    Kb[base + d]      = f2bf(k1 * c - k2 * sn);
    Kb[base + d + 64] = f2bf(k2 * c + k1 * sn);
}

// ---------------------------------------------------------------------------
// Causal MFMA flash attention, v2:
//  - 8 waves / 512 threads / 128 Q-rows per block (staging amortized 2x)
//  - Q fragments loaded straight global->reg (Qs LDS dropped: 62.5->54.3 KB)
//  - T14 async-STAGE split: next K/V tile global->reg before compute,
//    reg->LDS after the post-compute barrier (latency hidden under MFMA)
//  - per-wave causal skip of fully-masked tiles; T5 setprio around MFMA
// Q,K,V: [B][NH][S][HD] bf16 (Q pre-scaled); O: [B][S][NH][HD] bf16.
// ---------------------------------------------------------------------------
__global__ __launch_bounds__(512)
void flash_attn(const bf16* __restrict__ Qg, const bf16* __restrict__ Kg,
                const bf16* __restrict__ Vg, bf16* __restrict__ Og)
{
    constexpr int S = 2048;
    const int qb = blockIdx.x;            // 0..15, 128 Q rows each
    const int bh = blockIdx.y;
    const int b = bh >> 4, h = bh & 15;
    const size_t base = (size_t)bh * S * 128;
    const bf16* Qp = Qg + base;
    const bf16* Kp = Kg + base;
    const bf16* Vp = Vg + base;

    const int tid  = threadIdx.x;
    const int wave = tid >> 6;            // 0..7
    const int ln   = tid & 63;
    const int r15  = ln & 15;
    const int quad = ln >> 4;

    __shared__ bf16 Ks[64][136];          // K tile, 17.0 KB
    __shared__ bf16 Vt[128][72];          // V tile transposed, 18.0 KB
    __shared__ bf16 Ps[8][16][72];        // per-wave P round-trip, 18.0 KB

    const int qs    = qb * 128;
    const int qrow0 = qs + wave * 16;     // this wave's first Q row
    const int dt    = qrow0 >> 6;         // this wave's diagonal K-tile
    const int ktmax = 2 * qb + 1;         // last K-tile for this block

    // Q fragments straight from global (16 rows x 32B per wave, read once)
    short8 qf[4];
#pragma unroll
    for (int ks = 0; ks < 4; ++ks)
        qf[ks] = *(const short8*)&Qp[(size_t)(qrow0 + r15) * 128 + ks * 32 + quad * 8];

    float4_ acc_o[8];
    const float4_ fzero = {0.f, 0.f, 0.f, 0.f};
#pragma unroll
    for (int of = 0; of < 8; ++of) acc_o[of] = fzero;
    float m_run[4], l_run[4];
#pragma unroll
    for (int r = 0; r < 4; ++r) { m_run[r] = -__builtin_inff(); l_run[r] = 0.f; }

    // staging coordinates
    const int kr = tid >> 4;              // 0..31  (K row within half-tile)
    const int kc = (tid & 15) * 8;        // 0..120 (K col)
    const int vd = wave * 16;             // V d-column base for this wave

    // ---- stage tile 0 synchronously ----
    {
#pragma unroll
        for (int p = 0; p < 2; ++p)
            *(int4_*)&Ks[kr + p * 32][kc] =
                *(const int4_*)&Kp[(size_t)(kr + p * 32) * 128 + kc];
        union { int4_ v; bf16 h[8]; } u;
#pragma unroll
        for (int p = 0; p < 2; ++p) {
            u.v = *(const int4_*)&Vp[(size_t)ln * 128 + vd + p * 8];
#pragma unroll
            for (int j = 0; j < 8; ++j)
                Vt[vd + p * 8 + j][ln] = u.h[j];
        }
    }
    __syncthreads();

    for (int kt = 0; kt <= ktmax; ++kt) {
        const bool more = (kt < ktmax);

        // T14 issue-early: next tile's K/V global->reg, consumed after barrier
        int4_ kpre0, kpre1, vpre0, vpre1;
        if (more) {
            const int krow = (kt + 1) * 64;
            kpre0 = *(const int4_*)&Kp[(size_t)(krow + kr) * 128 + kc];
            kpre1 = *(const int4_*)&Kp[(size_t)(krow + kr + 32) * 128 + kc];
            vpre0 = *(const int4_*)&Vp[(size_t)(krow + ln) * 128 + vd];
            vpre1 = *(const int4_*)&Vp[(size_t)(krow + ln) * 128 + vd + 8];
        }

        if (kt <= dt) {                   // wave-uniform causal skip
            float4_ sacc[4];
            __builtin_amdgcn_s_setprio(1);
#pragma unroll
            for (int nf = 0; nf < 4; ++nf) {
                sacc[nf] = fzero;
#pragma unroll
                for (int ks = 0; ks < 4; ++ks) {
                    short8 kf = *(const short8*)&Ks[nf * 16 + r15][ks * 32 + quad * 8];
                    sacc[nf] = MFMA_BF16(qf[ks], kf, sacc[nf]);
                }
            }
            __builtin_amdgcn_s_setprio(0);

            if (kt == dt) {               // diagonal tile: element mask
                const int ro = (qrow0 & 63) + quad * 4;
#pragma unroll
                for (int nf = 0; nf < 4; ++nf) {
                    const int col = nf * 16 + r15;
#pragma unroll
                    for (int r = 0; r < 4; ++r)
                        if (col > ro + r) sacc[nf][r] = -__builtin_inff();
                }
            }

            float mnew[4], alpha[4];
#pragma unroll
            for (int r = 0; r < 4; ++r) {
                float rm = fmaxf(fmaxf(sacc[0][r], sacc[1][r]),
                                 fmaxf(sacc[2][r], sacc[3][r]));
                rm = fmaxf(rm, __shfl_xor(rm, 1));
                rm = fmaxf(rm, __shfl_xor(rm, 2));
                rm = fmaxf(rm, __shfl_xor(rm, 4));
                rm = fmaxf(rm, __shfl_xor(rm, 8));
                mnew[r]  = fmaxf(m_run[r], rm);
                alpha[r] = __expf(m_run[r] - mnew[r]);
                m_run[r] = mnew[r];
            }
            float rs[4] = {0.f, 0.f, 0.f, 0.f};
#pragma unroll
            for (int nf = 0; nf < 4; ++nf) {
#pragma unroll
                for (int r = 0; r < 4; ++r) {
                    const float p = __expf(sacc[nf][r] - mnew[r]);
                    rs[r] += p;
                    Ps[wave][quad * 4 + r][nf * 16 + r15] = f2bf(p);
                }
            }
#pragma unroll
            for (int r = 0; r < 4; ++r) {
                float t = rs[r];
                t += __shfl_xor(t, 1);
                t += __shfl_xor(t, 2);
                t += __shfl_xor(t, 4);
                t += __shfl_xor(t, 8);
                l_run[r] = l_run[r] * alpha[r] + t;
            }
#pragma unroll
            for (int of = 0; of < 8; ++of)
#pragma unroll
                for (int r = 0; r < 4; ++r)
                    acc_o[of][r] *= alpha[r];

            __builtin_amdgcn_s_setprio(1);
#pragma unroll
            for (int k2 = 0; k2 < 2; ++k2) {
                short8 pf = *(const short8*)&Ps[wave][r15][k2 * 32 + quad * 8];
#pragma unroll
                for (int of = 0; of < 8; ++of) {
                    short8 vf = *(const short8*)&Vt[of * 16 + r15][k2 * 32 + quad * 8];
                    acc_o[of] = MFMA_BF16(pf, vf, acc_o[of]);
                }
            }
            __builtin_amdgcn_s_setprio(0);
        }

        __syncthreads();                  // all waves done reading Ks/Vt
        if (more) {                       // T14 write-late: reg->LDS
            *(int4_*)&Ks[kr][kc]      = kpre0;
            *(int4_*)&Ks[kr + 32][kc] = kpre1;
            union { int4_ v; bf16 h[8]; } u;
            u.v = vpre0;
#pragma unroll
            for (int j = 0; j < 8; ++j) Vt[vd + j][ln] = u.h[j];
            u.v = vpre1;
#pragma unroll
            for (int j = 0; j < 8; ++j) Vt[vd + 8 + j][ln] = u.h[j];
        }
        __syncthreads();
    }

    // epilogue: O[b][s][h][d]
#pragma unroll
    for (int r = 0; r < 4; ++r) {
        const float inv = 1.f / l_run[r];
        const int  s  = qrow0 + quad * 4 + r;
        const size_t ob = (((size_t)b * S + s) * 16 + h) * 128;
#pragma unroll
        for (int of = 0; of < 8; ++of)
            Og[ob + of * 16 + r15] = f2bf(acc_o[of][r] * inv);
    }
}

// ---------------------------------------------------------------------------
extern "C" void kernel_launch(void* const* d_in, const int* in_sizes, int n_in,
                              void* d_out, int out_size, void* d_ws, size_t ws_size,
                              hipStream_t stream)
{
    // fp32 inputs in setup_inputs() dict order (verified r5/r6)
    const float* X  = (const float*)d_in[0];
    const float* Wq = (const float*)d_in[1];
    const float* Wk = (const float*)d_in[2];
    const float* Wv = (const float*)d_in[3];
    const float* Wo = (const float*)d_in[4];
    float* out = (float*)d_out;              // fp32 output (verified r6)

    // ws (bf16 elems): 112 MB total, ws >= 128 MB verified
    bf16* Xb  = (bf16*)d_ws;                 // 8388608
    bf16* Wqb = Xb  + 8388608;               // 4194304 each
    bf16* Wkb = Wqb + 4194304;
    bf16* Wvb = Wkb + 4194304;
    bf16* Wob = Wvb + 4194304;
    bf16* q   = Wob + 4194304;               // [B][NH][S][HD] 8388608 each
    bf16* k   = q   + 8388608;
    bf16* v   = k   + 8388608;
    bf16* ao  = v   + 8388608;               // [B][S][NH][HD]

    dim3 blk(256);
    cvt_all<<<dim3(12288), blk, 0, stream>>>(X, Wq, Wk, Wv, Wo,
                                             Xb, Wqb, Wkb, Wvb, Wob);
    gemm128<<<dim3(16, 32, 3), blk, 0, stream>>>(Xb, Wqb, Wkb, Wvb,
                                                 q, k, v, nullptr, 0);
    rope_scale<<<dim3((2 * 16 * 2048 * 64) / 256), blk, 0, stream>>>(q, k);
    flash_attn<<<dim3(16, 32), dim3(512), 0, stream>>>(q, k, v, ao);
    gemm128<<<dim3(16, 32, 1), blk, 0, stream>>>(ao, Wob, Wob, Wob,
                                                 nullptr, nullptr, nullptr, out, 1);
}